// Round 2
// baseline (264.959 us; speedup 1.0000x reference)
//
#include <hip/hip_runtime.h>
#include <stdint.h>

// ReconstructionDecoder: out[b,n,t,f,:] = relu(LN(x[b,n]+t_emb[t]+f_emb[f]) @ W1 + b1) @ W2 + b2
// B=2 N=8 T=128 F=128 D=256 E=512.  Rows M = 262144.
//
// Round 2: fix the round-1 scratch-spill catastrophe (WRITE_SIZE 250MB, VGPR=64 under
// launch_bounds(256,4) while afrag alone needs 64 VGPRs).
//  - launch_bounds(256,2): 256-reg unified budget -> afrag resident, no spills.
//  - register prefetch of next fragB chunk across the barrier (hide global latency).
//  - preps merged into one kernel; b1p reduction parallelized over k.

#define D_ 256
#define E_ 512

typedef __attribute__((ext_vector_type(8))) short short8;
typedef __attribute__((ext_vector_type(4))) float f32x4;

__device__ inline unsigned short f2bf(float f) {
  unsigned int u = __float_as_uint(f);
  u += 0x7fffu + ((u >> 16) & 1u);
  return (unsigned short)(u >> 16);
}

// frag[((jt*8 + ks)*64 + lane)*8 + j] = bf16( ln_g[k] * W1[k][e] )
//   k = ks*32 + (lane>>4)*8 + j, e = jt*16 + (lane&15)   (16x16x32 B-operand order)
// b1p[e] = b1[e] + sum_k ln_b[k] * W1[k][e]
__global__ __launch_bounds__(256) void prep(const float* __restrict__ W1,
                                            const float* __restrict__ ln_g,
                                            const float* __restrict__ ln_b,
                                            const float* __restrict__ b1,
                                            unsigned short* __restrict__ frag,
                                            float* __restrict__ b1p) {
  __shared__ float s[256];
  const int blk = blockIdx.x;
  const int tid = threadIdx.x;
  if (blk < 512) {
    int gid = blk * 256 + tid;  // 0..131071
    int j = gid & 7;
    int lane = (gid >> 3) & 63;
    int ks = (gid >> 9) & 7;
    int jt = gid >> 12;  // 0..31
    int k = ks * 32 + ((lane >> 4) & 3) * 8 + j;
    int e = jt * 16 + (lane & 15);
    frag[gid] = f2bf(ln_g[k] * W1[k * E_ + e]);
  } else {
    int bb = blk - 512;            // 0..31, 16 e's per block
    int e = bb * 16 + (tid & 15);
    int kb = (tid >> 4) * 16;      // 16 threads per e, 16 k's per thread
    float p = 0.f;
    for (int i = 0; i < 16; ++i) p = fmaf(ln_b[kb + i], W1[(kb + i) * E_ + e], p);
    s[tid] = p;
    __syncthreads();
    if (tid < 16) {
      float ssum = b1[bb * 16 + tid];
      for (int g = 0; g < 16; ++g) ssum += s[g * 16 + tid];
      b1p[bb * 16 + tid] = ssum;
    }
  }
}

__global__ __launch_bounds__(256, 2) void decoder_main(
    const float* __restrict__ x, const float* __restrict__ t_emb,
    const float* __restrict__ f_emb, const unsigned short* __restrict__ fragB,
    const float* __restrict__ b1p, const float* __restrict__ W2,
    const float* __restrict__ b2, float* __restrict__ out) {
  __shared__ float4 s_frag[2048];  // 32KB: 4 col-tiles (jt) worth of B fragments
  __shared__ float s_xt[D_];       // x[b,n,:] + t_emb[t,:]
  __shared__ float s_b1[E_];
  __shared__ float s_w2[2 * E_];
  __shared__ float s_out[256];

  const int tid = threadIdx.x;
  const int wave = tid >> 6;
  const int lane = tid & 63;
  const int quad = (lane >> 4) & 3;
  const int n16 = lane & 15;
  const int bIdx = blockIdx.x;  // (b*8+n)*128 + t  -> block covers f=0..127
  const int bn = bIdx >> 7;
  const int t = bIdx & 127;

  // prefetch chunk 0 of fragB into registers (overlaps with constant staging + A-build)
  const float4* src = reinterpret_cast<const float4*>(fragB);
  float4 pf[8];
#pragma unroll
  for (int i = 0; i < 8; ++i) pf[i] = src[tid + i * 256];

  // cooperative stage of per-block constants
  s_xt[tid] = x[bn * D_ + tid] + t_emb[t * D_ + tid];
  s_b1[tid] = b1p[tid];
  s_b1[tid + 256] = b1p[tid + 256];
  s_w2[tid] = W2[tid];
  s_w2[tid + 256] = W2[tid + 256];
  s_w2[tid + 512] = W2[tid + 512];
  s_w2[tid + 768] = W2[tid + 768];
  __syncthreads();

  // ---- build A fragments (LN-normalized h, bf16) for 2 row-groups of 16 ----
  short8 afrag[2][8];
#pragma unroll
  for (int g = 0; g < 2; ++g) {
    const int f = wave * 32 + g * 16 + n16;
    const float4* fe = reinterpret_cast<const float4*>(f_emb + f * D_);
    const float4* xt4 = reinterpret_cast<const float4*>(s_xt);
    float sum = 0.f, sq = 0.f;
#pragma unroll
    for (int ks = 0; ks < 8; ++ks) {
      int i0 = ks * 8 + quad * 2;
      float4 a0 = xt4[i0], a1 = xt4[i0 + 1];
      float4 c0 = fe[i0], c1 = fe[i0 + 1];
      float h0 = a0.x + c0.x, h1 = a0.y + c0.y, h2 = a0.z + c0.z, h3 = a0.w + c0.w;
      float h4 = a1.x + c1.x, h5 = a1.y + c1.y, h6 = a1.z + c1.z, h7 = a1.w + c1.w;
      sum += (h0 + h1 + h2 + h3) + (h4 + h5 + h6 + h7);
      sq = fmaf(h0, h0, sq); sq = fmaf(h1, h1, sq);
      sq = fmaf(h2, h2, sq); sq = fmaf(h3, h3, sq);
      sq = fmaf(h4, h4, sq); sq = fmaf(h5, h5, sq);
      sq = fmaf(h6, h6, sq); sq = fmaf(h7, h7, sq);
    }
    // row's 256 elems live in lanes {l, l^16, l^32, l^48}
    sum += __shfl_xor(sum, 16); sum += __shfl_xor(sum, 32);
    sq  += __shfl_xor(sq, 16);  sq  += __shfl_xor(sq, 32);
    float mu = sum * (1.0f / 256.0f);
    float var = sq * (1.0f / 256.0f) - mu * mu;
    float rs = rsqrtf(var + 1e-5f);
    float cc = -mu * rs;
#pragma unroll
    for (int ks = 0; ks < 8; ++ks) {
      int i0 = ks * 8 + quad * 2;
      float4 a0 = xt4[i0], a1 = xt4[i0 + 1];
      float4 c0 = fe[i0], c1 = fe[i0 + 1];
      union { unsigned short u[8]; short8 v; } fr;
      fr.u[0] = f2bf(fmaf(a0.x + c0.x, rs, cc));
      fr.u[1] = f2bf(fmaf(a0.y + c0.y, rs, cc));
      fr.u[2] = f2bf(fmaf(a0.z + c0.z, rs, cc));
      fr.u[3] = f2bf(fmaf(a0.w + c0.w, rs, cc));
      fr.u[4] = f2bf(fmaf(a1.x + c1.x, rs, cc));
      fr.u[5] = f2bf(fmaf(a1.y + c1.y, rs, cc));
      fr.u[6] = f2bf(fmaf(a1.z + c1.z, rs, cc));
      fr.u[7] = f2bf(fmaf(a1.w + c1.w, rs, cc));
      afrag[g][ks] = fr.v;
    }
  }

  // ---- main loop: 8 chunks x 4 col-tiles x 8 K-steps, reg-prefetch next chunk ----
  float oa[2][4][2] = {};
  const short8* sfrag8 = reinterpret_cast<const short8*>(s_frag);
  for (int ch = 0; ch < 8; ++ch) {
    __syncthreads();
#pragma unroll
    for (int i = 0; i < 8; ++i) s_frag[tid + i * 256] = pf[i];
    __syncthreads();
    if (ch < 7) {
      const float4* s2 = src + (ch + 1) * 2048;
#pragma unroll
      for (int i = 0; i < 8; ++i) pf[i] = s2[tid + i * 256];
    }
#pragma unroll
    for (int jtl = 0; jtl < 4; ++jtl) {
      f32x4 acc0 = {0.f, 0.f, 0.f, 0.f};
      f32x4 acc1 = {0.f, 0.f, 0.f, 0.f};
#pragma unroll
      for (int ks = 0; ks < 8; ++ks) {
        short8 bf = sfrag8[(jtl * 8 + ks) * 64 + lane];
        acc0 = __builtin_amdgcn_mfma_f32_16x16x32_bf16(afrag[0][ks], bf, acc0, 0, 0, 0);
        acc1 = __builtin_amdgcn_mfma_f32_16x16x32_bf16(afrag[1][ks], bf, acc1, 0, 0, 0);
      }
      int e = (ch * 4 + jtl) * 16 + n16;
      float bias = s_b1[e];
      float w0 = s_w2[2 * e], w1 = s_w2[2 * e + 1];
#pragma unroll
      for (int r = 0; r < 4; ++r) {
        float y0 = fmaxf(acc0[r] + bias, 0.f);
        float y1 = fmaxf(acc1[r] + bias, 0.f);
        oa[0][r][0] += y0 * w0; oa[0][r][1] += y0 * w1;
        oa[1][r][0] += y1 * w0; oa[1][r][1] += y1 * w1;
      }
    }
  }

  // ---- reduce over the 16 column-lanes, stage, coalesced store ----
#pragma unroll
  for (int g = 0; g < 2; ++g)
#pragma unroll
    for (int r = 0; r < 4; ++r)
#pragma unroll
      for (int o = 0; o < 2; ++o) {
        float v = oa[g][r][o];
        v += __shfl_xor(v, 1);
        v += __shfl_xor(v, 2);
        v += __shfl_xor(v, 4);
        v += __shfl_xor(v, 8);
        oa[g][r][o] = v;
      }
  if (n16 == 0) {
#pragma unroll
    for (int g = 0; g < 2; ++g)
#pragma unroll
      for (int r = 0; r < 4; ++r) {
        int lrow = wave * 32 + g * 16 + quad * 4 + r;  // = f
        s_out[lrow * 2 + 0] = oa[g][r][0];
        s_out[lrow * 2 + 1] = oa[g][r][1];
      }
  }
  __syncthreads();
  out[bIdx * 256 + tid] = s_out[tid] + b2[tid & 1];
}

extern "C" void kernel_launch(void* const* d_in, const int* in_sizes, int n_in,
                              void* d_out, int out_size, void* d_ws, size_t ws_size,
                              hipStream_t stream) {
  const float* x = (const float*)d_in[0];
  const float* t_emb = (const float*)d_in[1];
  const float* f_emb = (const float*)d_in[2];
  const float* ln_g = (const float*)d_in[3];
  const float* ln_b = (const float*)d_in[4];
  const float* W1 = (const float*)d_in[5];
  const float* b1 = (const float*)d_in[6];
  const float* W2 = (const float*)d_in[7];
  const float* b2 = (const float*)d_in[8];

  unsigned short* frag = (unsigned short*)d_ws;     // 131072 u16 = 256KB
  float* b1p = (float*)((char*)d_ws + 131072 * 2);  // 2KB

  prep<<<544, 256, 0, stream>>>(W1, ln_g, ln_b, b1, frag, b1p);
  decoder_main<<<2048, 256, 0, stream>>>(x, t_emb, f_emb, frag, b1p, W2, b2,
                                         (float*)d_out);
}

// Round 3
// 184.642 us; speedup vs baseline: 1.4350x; 1.4350x over previous
//
#include <hip/hip_runtime.h>
#include <stdint.h>

// ReconstructionDecoder: out[b,n,t,f,:] = relu(LN(x[b,n]+t_emb[t]+f_emb[f]) @ W1 + b1) @ W2 + b2
// B=2 N=8 T=128 F=128 D=256 E=512.  Rows M = 262144.
//
// Round 3: kill the spills for real.
//  - r2 lesson: launch_bounds(256,2) caps VGPR budget at 128; afrag(64)+pf(32)+misc blew it.
//  - fragB staging now via __builtin_amdgcn_global_load_lds width=16 (no VGPR round-trip),
//    ping-pong 2x16KB LDS buffers, ONE barrier per step (its implicit vmcnt(0) drain is the
//    load-complete wait); async loads for step s+1 issued right after the barrier, flying
//    during step s's 32 MFMAs.
//  - register demand ~105 <= 128 -> no spill at 2 blocks/CU (8 waves/CU).

#define D_ 256
#define E_ 512

typedef __attribute__((ext_vector_type(8))) short short8;
typedef __attribute__((ext_vector_type(4))) float f32x4;

typedef __attribute__((address_space(1))) void gvoid;
typedef __attribute__((address_space(3))) void lvoid;
#define GLOAD_LDS16(g, l) \
  __builtin_amdgcn_global_load_lds((gvoid*)(g), (lvoid*)(l), 16, 0, 0)

__device__ inline unsigned short f2bf(float f) {
  unsigned int u = __float_as_uint(f);
  u += 0x7fffu + ((u >> 16) & 1u);
  return (unsigned short)(u >> 16);
}

// frag[((jt*8 + ks)*64 + lane)*8 + j] = bf16( ln_g[k] * W1[k][e] )
//   k = ks*32 + (lane>>4)*8 + j, e = jt*16 + (lane&15)   (16x16x32 B-operand order)
// b1p[e] = b1[e] + sum_k ln_b[k] * W1[k][e]
__global__ __launch_bounds__(256) void prep(const float* __restrict__ W1,
                                            const float* __restrict__ ln_g,
                                            const float* __restrict__ ln_b,
                                            const float* __restrict__ b1,
                                            unsigned short* __restrict__ frag,
                                            float* __restrict__ b1p) {
  __shared__ float s[256];
  const int blk = blockIdx.x;
  const int tid = threadIdx.x;
  if (blk < 512) {
    int gid = blk * 256 + tid;  // 0..131071
    int j = gid & 7;
    int lane = (gid >> 3) & 63;
    int ks = (gid >> 9) & 7;
    int jt = gid >> 12;  // 0..31
    int k = ks * 32 + ((lane >> 4) & 3) * 8 + j;
    int e = jt * 16 + (lane & 15);
    frag[gid] = f2bf(ln_g[k] * W1[k * E_ + e]);
  } else {
    int bb = blk - 512;        // 0..31, 16 e's per block
    int e = bb * 16 + (tid & 15);
    int kb = (tid >> 4) * 16;  // 16 threads per e, 16 k's per thread
    float p = 0.f;
    for (int i = 0; i < 16; ++i) p = fmaf(ln_b[kb + i], W1[(kb + i) * E_ + e], p);
    s[tid] = p;
    __syncthreads();
    if (tid < 16) {
      float ssum = b1[bb * 16 + tid];
      for (int g = 0; g < 16; ++g) ssum += s[g * 16 + tid];
      b1p[bb * 16 + tid] = ssum;
    }
  }
}

__global__ __launch_bounds__(256, 2) void decoder_main(
    const float* __restrict__ x, const float* __restrict__ t_emb,
    const float* __restrict__ f_emb, const unsigned short* __restrict__ fragB,
    const float* __restrict__ b1p, const float* __restrict__ W2,
    const float* __restrict__ b2, float* __restrict__ out) {
  __shared__ short8 s_frag[2][1024];  // 2 x 16KB ping-pong (2 col-tiles each)
  __shared__ float s_xt[D_];          // x[b,n,:] + t_emb[t,:]
  __shared__ float s_b1[E_];
  __shared__ float s_w2[2 * E_];
  __shared__ float s_out[256];

  const int tid = threadIdx.x;
  const int wave = tid >> 6;
  const int lane = tid & 63;
  const int quad = (lane >> 4) & 3;
  const int n16 = lane & 15;
  const int bIdx = blockIdx.x;  // (b*8+n)*128 + t  -> block covers f=0..127
  const int bn = bIdx >> 7;
  const int t = bIdx & 127;

  // cooperative stage of per-block constants
  s_xt[tid] = x[bn * D_ + tid] + t_emb[t * D_ + tid];
  s_b1[tid] = b1p[tid];
  s_b1[tid + 256] = b1p[tid + 256];
  s_w2[tid] = W2[tid];
  s_w2[tid + 256] = W2[tid + 256];
  s_w2[tid + 512] = W2[tid + 512];
  s_w2[tid + 768] = W2[tid + 768];
  __syncthreads();

  // issue async staging of step-0 fragB chunk; it flies during the A-build
  const char* fragBb = (const char*)fragB;
#pragma unroll
  for (int i = 0; i < 4; ++i)
    GLOAD_LDS16(fragBb + (i * 256 + wave * 64 + lane) * 16,
                &s_frag[0][i * 256 + wave * 64]);

  // ---- build A fragments (LN-normalized h, bf16) for 2 row-groups of 16 ----
  short8 afrag[2][8];
#pragma unroll
  for (int g = 0; g < 2; ++g) {
    const int f = wave * 32 + g * 16 + n16;
    const float4* fe = reinterpret_cast<const float4*>(f_emb + f * D_);
    const float4* xt4 = reinterpret_cast<const float4*>(s_xt);
    float sum = 0.f, sq = 0.f;
#pragma unroll
    for (int ks = 0; ks < 8; ++ks) {
      int i0 = ks * 8 + quad * 2;
      float4 a0 = xt4[i0], a1 = xt4[i0 + 1];
      float4 c0 = fe[i0], c1 = fe[i0 + 1];
      float h0 = a0.x + c0.x, h1 = a0.y + c0.y, h2 = a0.z + c0.z, h3 = a0.w + c0.w;
      float h4 = a1.x + c1.x, h5 = a1.y + c1.y, h6 = a1.z + c1.z, h7 = a1.w + c1.w;
      sum += (h0 + h1 + h2 + h3) + (h4 + h5 + h6 + h7);
      sq = fmaf(h0, h0, sq); sq = fmaf(h1, h1, sq);
      sq = fmaf(h2, h2, sq); sq = fmaf(h3, h3, sq);
      sq = fmaf(h4, h4, sq); sq = fmaf(h5, h5, sq);
      sq = fmaf(h6, h6, sq); sq = fmaf(h7, h7, sq);
    }
    // row's 256 elems live in lanes {l, l^16, l^32, l^48}
    sum += __shfl_xor(sum, 16); sum += __shfl_xor(sum, 32);
    sq  += __shfl_xor(sq, 16);  sq  += __shfl_xor(sq, 32);
    float mu = sum * (1.0f / 256.0f);
    float var = sq * (1.0f / 256.0f) - mu * mu;
    float rs = rsqrtf(var + 1e-5f);
    float cc = -mu * rs;
#pragma unroll
    for (int ks = 0; ks < 8; ++ks) {
      int i0 = ks * 8 + quad * 2;
      float4 a0 = xt4[i0], a1 = xt4[i0 + 1];
      float4 c0 = fe[i0], c1 = fe[i0 + 1];
      union { unsigned short u[8]; short8 v; } fr;
      fr.u[0] = f2bf(fmaf(a0.x + c0.x, rs, cc));
      fr.u[1] = f2bf(fmaf(a0.y + c0.y, rs, cc));
      fr.u[2] = f2bf(fmaf(a0.z + c0.z, rs, cc));
      fr.u[3] = f2bf(fmaf(a0.w + c0.w, rs, cc));
      fr.u[4] = f2bf(fmaf(a1.x + c1.x, rs, cc));
      fr.u[5] = f2bf(fmaf(a1.y + c1.y, rs, cc));
      fr.u[6] = f2bf(fmaf(a1.z + c1.z, rs, cc));
      fr.u[7] = f2bf(fmaf(a1.w + c1.w, rs, cc));
      afrag[g][ks] = fr.v;
    }
  }

  // ---- main loop: 16 steps x (2 col-tiles x 8 K-steps), single barrier per step ----
  // barrier's implicit vmcnt(0) drain == "loads for cur complete"; then issue nxt's loads
  // so they overlap cur's 32 MFMAs.
  float oa[2][4][2] = {};
  for (int s = 0; s < 16; ++s) {
    __syncthreads();  // all waves' async loads for buf[s&1] drained + visible
    if (s < 15) {
      const char* gchunk = fragBb + (s + 1) * 16384;
      short8* nb = s_frag[(s + 1) & 1];
#pragma unroll
      for (int i = 0; i < 4; ++i)
        GLOAD_LDS16(gchunk + (i * 256 + wave * 64 + lane) * 16,
                    &nb[i * 256 + wave * 64]);
    }
    const short8* bf8 = s_frag[s & 1];
#pragma unroll
    for (int jl = 0; jl < 2; ++jl) {
      f32x4 acc0 = {0.f, 0.f, 0.f, 0.f};
      f32x4 acc1 = {0.f, 0.f, 0.f, 0.f};
#pragma unroll
      for (int ks = 0; ks < 8; ++ks) {
        short8 bf = bf8[(jl * 8 + ks) * 64 + lane];
        acc0 = __builtin_amdgcn_mfma_f32_16x16x32_bf16(afrag[0][ks], bf, acc0, 0, 0, 0);
        acc1 = __builtin_amdgcn_mfma_f32_16x16x32_bf16(afrag[1][ks], bf, acc1, 0, 0, 0);
      }
      int e = (s * 2 + jl) * 16 + n16;
      float bias = s_b1[e];
      float w0 = s_w2[2 * e], w1 = s_w2[2 * e + 1];
#pragma unroll
      for (int r = 0; r < 4; ++r) {
        float y0 = fmaxf(acc0[r] + bias, 0.f);
        float y1 = fmaxf(acc1[r] + bias, 0.f);
        oa[0][r][0] += y0 * w0; oa[0][r][1] += y0 * w1;
        oa[1][r][0] += y1 * w0; oa[1][r][1] += y1 * w1;
      }
    }
  }

  // ---- reduce over the 16 column-lanes, stage, coalesced store ----
#pragma unroll
  for (int g = 0; g < 2; ++g)
#pragma unroll
    for (int r = 0; r < 4; ++r)
#pragma unroll
      for (int o = 0; o < 2; ++o) {
        float v = oa[g][r][o];
        v += __shfl_xor(v, 1);
        v += __shfl_xor(v, 2);
        v += __shfl_xor(v, 4);
        v += __shfl_xor(v, 8);
        oa[g][r][o] = v;
      }
  if (n16 == 0) {
#pragma unroll
    for (int g = 0; g < 2; ++g)
#pragma unroll
      for (int r = 0; r < 4; ++r) {
        int lrow = wave * 32 + g * 16 + quad * 4 + r;  // = f
        s_out[lrow * 2 + 0] = oa[g][r][0];
        s_out[lrow * 2 + 1] = oa[g][r][1];
      }
  }
  __syncthreads();
  out[bIdx * 256 + tid] = s_out[tid] + b2[tid & 1];
}

extern "C" void kernel_launch(void* const* d_in, const int* in_sizes, int n_in,
                              void* d_out, int out_size, void* d_ws, size_t ws_size,
                              hipStream_t stream) {
  const float* x = (const float*)d_in[0];
  const float* t_emb = (const float*)d_in[1];
  const float* f_emb = (const float*)d_in[2];
  const float* ln_g = (const float*)d_in[3];
  const float* ln_b = (const float*)d_in[4];
  const float* W1 = (const float*)d_in[5];
  const float* b1 = (const float*)d_in[6];
  const float* W2 = (const float*)d_in[7];
  const float* b2 = (const float*)d_in[8];

  unsigned short* frag = (unsigned short*)d_ws;     // 131072 u16 = 256KB
  float* b1p = (float*)((char*)d_ws + 131072 * 2);  // 2KB

  prep<<<544, 256, 0, stream>>>(W1, ln_g, ln_b, b1, frag, b1p);
  decoder_main<<<2048, 256, 0, stream>>>(x, t_emb, f_emb, frag, b1p, W2, b2,
                                         (float*)d_out);
}